// Round 11
// baseline (353.016 us; speedup 1.0000x reference)
//
#include <hip/hip_runtime.h>
#include <math.h>

typedef __bf16 bf16;
typedef __bf16 bf16x4 __attribute__((ext_vector_type(4)));
typedef __bf16 bf16x8 __attribute__((ext_vector_type(8)));
typedef unsigned short u16;
typedef unsigned short u16x4 __attribute__((ext_vector_type(4)));
typedef unsigned short u16x8 __attribute__((ext_vector_type(8)));
typedef float f32x4 __attribute__((ext_vector_type(4)));
typedef float f32x16 __attribute__((ext_vector_type(16)));
typedef unsigned int u32x4 __attribute__((ext_vector_type(4)));

// ---------------------------------------------------------------------------
// prep_all: merged weight-prep (one launch instead of two).
// blocks [0,392): Wl1 f32 [12544][128] -> bf16 [128][12544], K permuted
//   k' = site*64+cout <-> Wl1 row k = cout*196+site.  s=b>>1, cg=b&1.
// blocks [392,466): W2 -> conv2 B-frag buffer w2r; W1 -> conv1 B-frag w1f.
// ---------------------------------------------------------------------------
__global__ void prep_all(const float* __restrict__ W2, bf16* __restrict__ w2r,
                         const float* __restrict__ W1, bf16* __restrict__ w1f,
                         const float* __restrict__ Wl1, bf16* __restrict__ wl1t) {
    __shared__ float tile[32 * 129];
    const int b = blockIdx.x;
    const int t = threadIdx.x;
    if (b < 392) {
        const int s  = b >> 1;
        const int cg = b & 1;
        for (int e = t; e < 4096; e += 256) {
            int cl = e >> 7, n = e & 127;
            tile[cl * 129 + n] = Wl1[((long)(cg * 32 + cl) * 196 + s) * 128 + n];
        }
        __syncthreads();
        for (int e = t; e < 4096; e += 256) {
            int n = e >> 5, cl = e & 31;
            wl1t[(long)n * 12544 + s * 64 + cg * 32 + cl] = (bf16)tile[cl * 129 + n];
        }
    } else {
        int e = (b - 392) * 256 + t;
        if (e < 18432) {
            int j  = e & 7;
            int l  = (e >> 3) & 63;
            int f  = e >> 9;
            int s  = f >> 1;
            int nt = f & 1;
            int tap  = s >> 1;
            int ci   = (s & 1) * 16 + (l >> 5) * 8 + j;
            int cout = nt * 32 + (l & 31);
            w2r[e] = (bf16)W2[cout * 288 + ci * 9 + tap];
        } else {
            int e2 = e - 18432;
            if (e2 < 512) {
                int j = e2 & 7;
                int l = e2 >> 3;
                int k = (l >> 5) * 8 + j;       // tap index (K)
                int n = l & 31;                 // cout
                w1f[e2] = (k < 9) ? (bf16)W1[n * 9 + k] : (bf16)0.f;
            }
        }
    }
}

// ---------------------------------------------------------------------------
// conv_fused R21 (FROZEN this round — structural local limit ~162 us):
// LDS pipe ~60%, VALU ~59%, MFMA ~36%, occupancy reg-pinned at 3 blk/CU.
// Levers measured null: occupancy (R18/R19 spill), MFMA chains (R20
// neutral), bank conflicts (R21: 1.75e7 -> 3.3e6, dur unchanged).
// !! (256,4) FORBIDDEN (R18/R19).  e0a/e1a additive only (R14).  LDS
// fills > 256 elems: strided loops (R8).
// h1s: addr(R,C,ci) = R*1024 + C*32 + (ci ^ ((((C>>1)^R)&3)<<3)).
// ---------------------------------------------------------------------------
__global__ __launch_bounds__(256, 3)
void conv_fused(const float* __restrict__ x, const float* __restrict__ b1,
                const bf16* __restrict__ w2r, const bf16* __restrict__ w1f,
                const float* __restrict__ b2, bf16* __restrict__ pooled)
{
    __shared__ __attribute__((aligned(16))) bf16  h1s[16 * 1024];   // 32768 B
    __shared__ __attribute__((aligned(16))) float mneg[98 * 4];     //  1568 B
    __shared__ __attribute__((aligned(16))) bf16  xs[640];          //  1280 B

    const int t    = threadIdx.x;
    const int lane = t & 63;
    const int wv   = t >> 6;
    const int img  = blockIdx.x >> 1;
    const int hb   = blockIdx.x & 1;        // image half
    const int nt   = wv & 1;                // conv2 cout half
    const int wp   = wv >> 1;               // conv2 Mt parity
    const int ml31 = lane & 31;
    const int lg   = lane >> 5;

    const float* xi = x + img * 784;

    // global loads early (L2-resident; latency hides behind staging)
    bf16x8 breg[18];
    {
        const bf16x8* wp2 = (const bf16x8*)w2r;
        #pragma unroll
        for (int s = 0; s < 18; s++)
            breg[s] = wp2[(2 * s + nt) * 64 + lane];
    }
    const bf16x8 w1frag = *(const bf16x8*)&w1f[lane * 8];
    const float  bias2  = b2[nt * 32 + ml31];
    // conv1 bias, per-reg (cout = 4*lg + 8*run + j)
    f32x4 bq[4];
    #pragma unroll
    for (int run = 0; run < 4; run++)
        bq[run] = *(const f32x4*)&b1[4 * lg + 8 * run];

    // stage x tile (bf16): xs[j*32+c] = x[hb*14-2+j][c-1], rows 0..19 (pad)
    for (int e = t; e < 640; e += 256) {
        int j  = e >> 5;
        int c  = e & 31;
        int xr = hb * 14 - 2 + j;
        int xc = c - 1;
        float v = 0.f;
        if (xr >= 0 && xr < 28 && xc >= 0 && xc < 28) v = xi[xr * 28 + xc];
        xs[e] = (bf16)v;
    }
    __syncthreads();

    const u16* xu = (const u16*)xs;

    // mneg: 392 entries > 256 threads -> strided loop (R8 lesson)
    for (int e = t; e < 392; e += 256) {
        int s   = e >> 2, q = e & 3;
        int spi = s / 14, spj = s - spi * 14;
        u16 cv = xu[(2 * spi + (q >> 1) + 2) * 32 + 2 * spj + (q & 1) + 1];
        mneg[e] = ((cv & 0x7fff) != 0) ? 0.f : -1e30f;
    }

    // ---- conv1 via MFMA 32x32x16, im2col fused, operand-swapped (R16).
    // B-operand (af): lane = position col = ml31; lg picks K-half (taps).
    #pragma unroll 1
    for (int Mt = wv; Mt < 16; Mt += 4) {
        const int bb = Mt * 32 + ml31 - 1;      // window base in xu
        u16x8 tv;
        if (lg == 0) {
            tv[0] = xu[bb];      tv[1] = xu[bb + 1];  tv[2] = xu[bb + 2];
            tv[3] = xu[bb + 32]; tv[4] = xu[bb + 33]; tv[5] = xu[bb + 34];
            tv[6] = xu[bb + 64]; tv[7] = xu[bb + 65];
        } else {
            #pragma unroll
            for (int j = 0; j < 8; j++) tv[j] = 0;
            tv[0] = xu[bb + 66];                // tap 8
        }
        bf16x8 af = *(bf16x8*)&tv;

        f32x16 acc;
        #pragma unroll
        for (int run = 0; run < 4; run++)
            #pragma unroll
            for (int j = 0; j < 4; j++) acc[run * 4 + j] = bq[run][j];
        acc = __builtin_amdgcn_mfma_f32_32x32x16_bf16(w1frag, af, acc, 0, 0, 0);

        // mask: uniform per lane (one position)
        u16 ctr = xu[(Mt + 1) * 32 + ml31];
        const bool ok = (ml31 >= 1) && (ml31 <= 28) && ((ctr & 0x7fff) != 0);
        // write: addr = Mt*1024 + col*32 + (ci0 ^ swz), swz=(((col>>1)^Mt)&3)<<3
        // (ci0^swz) = 4*lg + 8*(run^hi2) since ci0=4lg+8run, swz hits bits 3-4.
        const int hi2w  = ((ml31 >> 1) ^ Mt) & 3;
        const int wbase = (Mt << 10) + ml31 * 32 + 4 * lg;
        #pragma unroll
        for (int run = 0; run < 4; run++) {
            bf16x4 w4;
            #pragma unroll
            for (int j = 0; j < 4; j++) {
                float s = acc[run * 4 + j];
                w4[j] = (bf16)(ok ? fmaxf(s, 0.f) : 0.f);   // select: NaN-safe
            }
            *(bf16x4*)&h1s[wbase + 8 * (run ^ hi2w)] = w4;
        }
    }
    __syncthreads();    // h1s + mneg ready

    // ---- conv2 Mt loop (13 tiles of 32 M-rows, 98 pooled sites)
    const int cib = lg * 8;

    int q  = ml31 & 3;
    int pj = wp * 8 + (ml31 >> 2);
    int pi = 0;
    if (pj >= 14) { pj -= 14; pi = 1; }

    bf16* pout = pooled + (long)img * 12544 + hb * 98 * 64 + nt * 32 + ml31;

    #pragma unroll 1
    for (int Mt = wp; Mt < 13; Mt += 2) {
        int row = 2 * pi + (q >> 1);
        if (row > 13) row = 13;             // keep reads (row+2) in bounds
        int colb = 2 * pj + (q & 1);

        // Dual accumulators (R20; measured neutral, kept for chain ILP).
        f32x16 accE, accO;
        #pragma unroll
        for (int e = 0; e < 16; e++) { accE[e] = bias2; accO[e] = 0.f; }

        #pragma unroll
        for (int dr = 0; dr < 3; dr++) {
            const int R  = row + dr;
            const int rb = R << 10;         // * 1024
            #pragma unroll
            for (int dc = 0; dc < 3; dc++) {
                const int tap  = dr * 3 + dc;
                const int cc   = colb + dc;
                const int sw   = (((cc >> 1) ^ R) & 3) << 3;
                const int base = rb + cc * 32;
                bf16x8 a0 = *(const bf16x8*)&h1s[base + (cib ^ sw)];
                bf16x8 a1 = *(const bf16x8*)&h1s[base + ((16 + cib) ^ sw)];
                accE = __builtin_amdgcn_mfma_f32_32x32x16_bf16(a0, breg[2 * tap],     accE, 0, 0, 0);
                accO = __builtin_amdgcn_mfma_f32_32x32x16_bf16(a1, breg[2 * tap + 1], accO, 0, 0, 0);
            }
        }

        int slg = 8 * Mt + lg;
        #pragma unroll
        for (int gg = 0; gg < 4; gg++) {
            if (slg < 98) {
                f32x4 mn = *(const f32x4*)&mneg[slg * 4];
                float v0 = accE[gg * 4 + 0] + accO[gg * 4 + 0] + mn[0];
                float v1 = accE[gg * 4 + 1] + accO[gg * 4 + 1] + mn[1];
                float v2 = accE[gg * 4 + 2] + accO[gg * 4 + 2] + mn[2];
                float v3 = accE[gg * 4 + 3] + accO[gg * 4 + 3] + mn[3];
                float pm = fmaxf(fmaxf(v0, v1), fmaxf(v2, v3));
                pout[slg * 64] = (bf16)fmaxf(pm, 0.f);
            }
            slg += 2;
        }

        pj += 2; if (pj >= 14) { pj -= 14; pi += 1; }
        pi += 1;
    }
}

// ---------------------------------------------------------------------------
// fc1 R22: ZERO-LDS, ZERO-BARRIER streaming GEMM.
// The R12/R13 staged path's jq-permutation and aoff/boff XOR cancel
// exactly (verified algebraically): each lane's fragment is the contiguous
// 16B span  pooled[m0+am][k0+kt*64+s*32+kg*8]  (A) and
// wl1t[wn*64+j*16+ml][same k] (B).  So load fragments DIRECTLY from
// global: no As/Bs, no __syncthreads, no vmcnt(0) drain per iteration
// (the m97 structural stall R13 only partially dodged).  B rows are read
// by all 128 m-blocks -> L2-resident (wl1t 3.2 MB < 4 MB/XCD L2); A is
// 64B/row wave-coalesced, wm-duplicate read hits L2.  Free-running waves
// + compiler pipelining hide L2 latency; occupancy no longer matters
// structurally.  VGPR ~70, no spill expected at (256,4)'s 128 cap.
// ---------------------------------------------------------------------------
__global__ __launch_bounds__(256, 4)
void fc1(const bf16* __restrict__ pooled, const bf16* __restrict__ wl1t,
         float* __restrict__ part)
{
    const int t    = threadIdx.x;
    const int lane = t & 63;
    const int wv   = t >> 6;
    const int ml   = lane & 15;
    const int kg   = lane >> 4;
    const int wm   = wv & 1;
    const int wn   = wv >> 1;
    const int m0   = blockIdx.x * 32;
    const int ks   = blockIdx.y;
    const int k0   = ks * 1792;

    const int am = wm * 16 + ml;
    const bf16* ap = pooled + (long)(m0 + am) * 12544 + k0 + kg * 8;
    const bf16* bp0 = wl1t + (long)(wn * 64 + 0 * 16 + ml) * 12544 + k0 + kg * 8;
    const bf16* bp1 = wl1t + (long)(wn * 64 + 1 * 16 + ml) * 12544 + k0 + kg * 8;
    const bf16* bp2 = wl1t + (long)(wn * 64 + 2 * 16 + ml) * 12544 + k0 + kg * 8;
    const bf16* bp3 = wl1t + (long)(wn * 64 + 3 * 16 + ml) * 12544 + k0 + kg * 8;

    f32x4 acc[4];
    {
        f32x4 z = {0.f, 0.f, 0.f, 0.f};
        #pragma unroll
        for (int j = 0; j < 4; j++) acc[j] = z;
    }

    #pragma unroll 2
    for (int kt = 0; kt < 28; kt++) {
        const int kb = kt * 64;
        #pragma unroll
        for (int s = 0; s < 2; s++) {
            const int ko = kb + s * 32;
            bf16x8 af = *(const bf16x8*)(ap + ko);
            acc[0] = __builtin_amdgcn_mfma_f32_16x16x32_bf16(af, *(const bf16x8*)(bp0 + ko), acc[0], 0, 0, 0);
            acc[1] = __builtin_amdgcn_mfma_f32_16x16x32_bf16(af, *(const bf16x8*)(bp1 + ko), acc[1], 0, 0, 0);
            acc[2] = __builtin_amdgcn_mfma_f32_16x16x32_bf16(af, *(const bf16x8*)(bp2 + ko), acc[2], 0, 0, 0);
            acc[3] = __builtin_amdgcn_mfma_f32_16x16x32_bf16(af, *(const bf16x8*)(bp3 + ko), acc[3], 0, 0, 0);
        }
    }

    float* pp = part + ((long)ks * 4096 + m0 + wm * 16) * 128 + wn * 64;
    #pragma unroll
    for (int j = 0; j < 4; j++)
        #pragma unroll
        for (int r = 0; r < 4; r++)
            pp[(kg * 4 + r) * 128 + j * 16 + ml] = acc[j][r];
}

// ---------------------------------------------------------------------------
// fc2_lsm: one wave per image; 7-way split-K reduce + FC2 + log_softmax.
// ---------------------------------------------------------------------------
__global__ __launch_bounds__(256)
void fc2_lsm(const float* __restrict__ part, const float* __restrict__ bl1,
             const float* __restrict__ Wl2, const float* __restrict__ bl2,
             float* __restrict__ out)
{
    const int wv   = threadIdx.x >> 6;
    const int lane = threadIdx.x & 63;
    const int img  = blockIdx.x * 4 + wv;
    const float* pb = part + (long)img * 128;

    float ac[10];
    #pragma unroll
    for (int c = 0; c < 10; c++) ac[c] = 0.f;

    #pragma unroll
    for (int u = 0; u < 2; u++) {
        int n = lane + 64 * u;
        float s = bl1[n];
        #pragma unroll
        for (int k = 0; k < 7; k++) s += pb[(long)k * 4096 * 128 + n];
        float h = s > 0.f ? s : 0.f;
        #pragma unroll
        for (int c = 0; c < 10; c++) ac[c] += h * Wl2[n * 10 + c];
    }
    #pragma unroll
    for (int o = 32; o > 0; o >>= 1)
        #pragma unroll
        for (int c = 0; c < 10; c++) ac[c] += __shfl_down(ac[c], o, 64);

    if (lane == 0) {
        float lg[10], mx = -1e30f;
        #pragma unroll
        for (int c = 0; c < 10; c++) {
            lg[c] = ac[c] + bl2[c];
            mx = lg[c] > mx ? lg[c] : mx;
        }
        float se = 0.f;
        #pragma unroll
        for (int c = 0; c < 10; c++) se += __expf(lg[c] - mx);
        float ls = __logf(se);
        #pragma unroll
        for (int c = 0; c < 10; c++) out[img * 10 + c] = lg[c] - mx - ls;
    }
}

// ---------------------------------------------------------------------------
extern "C" void kernel_launch(void* const* d_in, const int* in_sizes, int n_in,
                              void* d_out, int out_size, void* d_ws, size_t ws_size,
                              hipStream_t stream) {
    const float* x   = (const float*)d_in[0];
    const float* W1  = (const float*)d_in[1];
    const float* b1  = (const float*)d_in[2];
    const float* W2  = (const float*)d_in[3];
    const float* b2  = (const float*)d_in[4];
    const float* Wl1 = (const float*)d_in[5];
    const float* bl1 = (const float*)d_in[6];
    const float* Wl2 = (const float*)d_in[7];
    const float* bl2 = (const float*)d_in[8];
    float* out = (float*)d_out;

    char* ws = (char*)d_ws;
    bf16*  w2r    = (bf16*)ws;                                   // 36,864 B
    bf16*  w1f    = (bf16*)(ws + 40960);                         //  1,024 B
    bf16*  wl1t   = (bf16*)(ws + 65536);                         // 3,211,264 B
    bf16*  pooled = (bf16*)(ws + 65536 + 4194304);               // 102,760,448 B
    float* part   = (float*)(ws + 65536 + 4194304 + 102760448);  // 14,680,064 B

    prep_all  <<<466,            256, 0, stream>>>(W2, w2r, W1, w1f, Wl1, wl1t);
    conv_fused<<<8192,           256, 0, stream>>>(x, b1, w2r, w1f, b2, pooled);
    fc1       <<<dim3(128, 7),   256, 0, stream>>>(pooled, wl1t, part);
    fc2_lsm   <<<1024,           256, 0, stream>>>(part, bl1, Wl2, bl2, out);
}

// Round 12
// 256.672 us; speedup vs baseline: 1.3754x; 1.3754x over previous
//
#include <hip/hip_runtime.h>
#include <math.h>

typedef __bf16 bf16;
typedef __bf16 bf16x4 __attribute__((ext_vector_type(4)));
typedef __bf16 bf16x8 __attribute__((ext_vector_type(8)));
typedef unsigned short u16;
typedef unsigned short u16x4 __attribute__((ext_vector_type(4)));
typedef unsigned short u16x8 __attribute__((ext_vector_type(8)));
typedef float f32x4 __attribute__((ext_vector_type(4)));
typedef float f32x16 __attribute__((ext_vector_type(16)));
typedef unsigned int u32x4 __attribute__((ext_vector_type(4)));

// ---------------------------------------------------------------------------
// prep_all R23: SHRUNK to 74 blocks — only w2r (conv2 B-frags) and w1f
// (conv1 B-frags).  The Wl1 transpose (392 blocks, ~6-10 us serial) moved
// into conv_fused's tail blocks, which run concurrently with other conv
// work and finish before fc1 launches.
// ---------------------------------------------------------------------------
__global__ void prep_all(const float* __restrict__ W2, bf16* __restrict__ w2r,
                         const float* __restrict__ W1, bf16* __restrict__ w1f) {
    int e = blockIdx.x * 256 + threadIdx.x;
    if (e < 18432) {
        int j  = e & 7;
        int l  = (e >> 3) & 63;
        int f  = e >> 9;
        int s  = f >> 1;
        int nt = f & 1;
        int tap  = s >> 1;
        int ci   = (s & 1) * 16 + (l >> 5) * 8 + j;
        int cout = nt * 32 + (l & 31);
        w2r[e] = (bf16)W2[cout * 288 + ci * 9 + tap];
    } else {
        int e2 = e - 18432;
        if (e2 < 512) {
            int j = e2 & 7;
            int l = e2 >> 3;
            int k = (l >> 5) * 8 + j;       // tap index (K)
            int n = l & 31;                 // cout
            w1f[e2] = (k < 9) ? (bf16)W1[n * 9 + k] : (bf16)0.f;
        }
    }
}

// ---------------------------------------------------------------------------
// conv_fused R23 = R21 (frozen at its ~162 us structural local limit) +
// Wl1-TRANSPOSE EPILOGUE in blocks 0..391: after conv2, reuse h1s (32.8KB
// >= 16.5KB tile) to do prep_all's old Wl1 f32 [12544][128] -> bf16
// [128][12544] chunk (s = b>>1, cg = b&1).  blockIdx-uniform branch ->
// barriers safe; leading __syncthreads() ensures conv2's h1s reads are
// done.  wl1t consumed only by fc1 (launches after conv) -> no race.
// R21 status: LDS ~60%, VALU ~59%, MFMA ~36%, reg-pinned 3 blk/CU.
// Null levers: occupancy (R18/R19 spill -> (256,4) FORBIDDEN), MFMA
// chains (R20 neutral), bank conflicts (R21: 1.75e7 -> 3.3e6, dur flat).
// !! e0a/e1a additive only (R14).  LDS fills > 256 elems: strided (R8).
// h1s: addr(R,C,ci) = R*1024 + C*32 + (ci ^ ((((C>>1)^R)&3)<<3)).
// ---------------------------------------------------------------------------
__global__ __launch_bounds__(256, 3)
void conv_fused(const float* __restrict__ x, const float* __restrict__ b1,
                const bf16* __restrict__ w2r, const bf16* __restrict__ w1f,
                const float* __restrict__ b2, bf16* __restrict__ pooled,
                const float* __restrict__ Wl1, bf16* __restrict__ wl1t)
{
    __shared__ __attribute__((aligned(16))) bf16  h1s[16 * 1024];   // 32768 B
    __shared__ __attribute__((aligned(16))) float mneg[98 * 4];     //  1568 B
    __shared__ __attribute__((aligned(16))) bf16  xs[640];          //  1280 B

    const int t    = threadIdx.x;
    const int lane = t & 63;
    const int wv   = t >> 6;
    const int img  = blockIdx.x >> 1;
    const int hb   = blockIdx.x & 1;        // image half
    const int nt   = wv & 1;                // conv2 cout half
    const int wp   = wv >> 1;               // conv2 Mt parity
    const int ml31 = lane & 31;
    const int lg   = lane >> 5;

    const float* xi = x + img * 784;

    // global loads early (L2-resident; latency hides behind staging)
    bf16x8 breg[18];
    {
        const bf16x8* wp2 = (const bf16x8*)w2r;
        #pragma unroll
        for (int s = 0; s < 18; s++)
            breg[s] = wp2[(2 * s + nt) * 64 + lane];
    }
    const bf16x8 w1frag = *(const bf16x8*)&w1f[lane * 8];
    const float  bias2  = b2[nt * 32 + ml31];
    // conv1 bias, per-reg (cout = 4*lg + 8*run + j)
    f32x4 bq[4];
    #pragma unroll
    for (int run = 0; run < 4; run++)
        bq[run] = *(const f32x4*)&b1[4 * lg + 8 * run];

    // stage x tile (bf16): xs[j*32+c] = x[hb*14-2+j][c-1], rows 0..19 (pad)
    for (int e = t; e < 640; e += 256) {
        int j  = e >> 5;
        int c  = e & 31;
        int xr = hb * 14 - 2 + j;
        int xc = c - 1;
        float v = 0.f;
        if (xr >= 0 && xr < 28 && xc >= 0 && xc < 28) v = xi[xr * 28 + xc];
        xs[e] = (bf16)v;
    }
    __syncthreads();

    const u16* xu = (const u16*)xs;

    // mneg: 392 entries > 256 threads -> strided loop (R8 lesson)
    for (int e = t; e < 392; e += 256) {
        int s   = e >> 2, q = e & 3;
        int spi = s / 14, spj = s - spi * 14;
        u16 cv = xu[(2 * spi + (q >> 1) + 2) * 32 + 2 * spj + (q & 1) + 1];
        mneg[e] = ((cv & 0x7fff) != 0) ? 0.f : -1e30f;
    }

    // ---- conv1 via MFMA 32x32x16, im2col fused, operand-swapped (R16).
    // B-operand (af): lane = position col = ml31; lg picks K-half (taps).
    #pragma unroll 1
    for (int Mt = wv; Mt < 16; Mt += 4) {
        const int bb = Mt * 32 + ml31 - 1;      // window base in xu
        u16x8 tv;
        if (lg == 0) {
            tv[0] = xu[bb];      tv[1] = xu[bb + 1];  tv[2] = xu[bb + 2];
            tv[3] = xu[bb + 32]; tv[4] = xu[bb + 33]; tv[5] = xu[bb + 34];
            tv[6] = xu[bb + 64]; tv[7] = xu[bb + 65];
        } else {
            #pragma unroll
            for (int j = 0; j < 8; j++) tv[j] = 0;
            tv[0] = xu[bb + 66];                // tap 8
        }
        bf16x8 af = *(bf16x8*)&tv;

        f32x16 acc;
        #pragma unroll
        for (int run = 0; run < 4; run++)
            #pragma unroll
            for (int j = 0; j < 4; j++) acc[run * 4 + j] = bq[run][j];
        acc = __builtin_amdgcn_mfma_f32_32x32x16_bf16(w1frag, af, acc, 0, 0, 0);

        // mask: uniform per lane (one position)
        u16 ctr = xu[(Mt + 1) * 32 + ml31];
        const bool ok = (ml31 >= 1) && (ml31 <= 28) && ((ctr & 0x7fff) != 0);
        // write: addr = Mt*1024 + col*32 + (ci0 ^ swz), swz=(((col>>1)^Mt)&3)<<3
        // (ci0^swz) = 4*lg + 8*(run^hi2) since ci0=4lg+8run, swz hits bits 3-4.
        const int hi2w  = ((ml31 >> 1) ^ Mt) & 3;
        const int wbase = (Mt << 10) + ml31 * 32 + 4 * lg;
        #pragma unroll
        for (int run = 0; run < 4; run++) {
            bf16x4 w4;
            #pragma unroll
            for (int j = 0; j < 4; j++) {
                float s = acc[run * 4 + j];
                w4[j] = (bf16)(ok ? fmaxf(s, 0.f) : 0.f);   // select: NaN-safe
            }
            *(bf16x4*)&h1s[wbase + 8 * (run ^ hi2w)] = w4;
        }
    }
    __syncthreads();    // h1s + mneg ready

    // ---- conv2 Mt loop (13 tiles of 32 M-rows, 98 pooled sites)
    const int cib = lg * 8;

    int q  = ml31 & 3;
    int pj = wp * 8 + (ml31 >> 2);
    int pi = 0;
    if (pj >= 14) { pj -= 14; pi = 1; }

    bf16* pout = pooled + (long)img * 12544 + hb * 98 * 64 + nt * 32 + ml31;

    #pragma unroll 1
    for (int Mt = wp; Mt < 13; Mt += 2) {
        int row = 2 * pi + (q >> 1);
        if (row > 13) row = 13;             // keep reads (row+2) in bounds
        int colb = 2 * pj + (q & 1);

        // Dual accumulators (R20; measured neutral, kept for chain ILP).
        f32x16 accE, accO;
        #pragma unroll
        for (int e = 0; e < 16; e++) { accE[e] = bias2; accO[e] = 0.f; }

        #pragma unroll
        for (int dr = 0; dr < 3; dr++) {
            const int R  = row + dr;
            const int rb = R << 10;         // * 1024
            #pragma unroll
            for (int dc = 0; dc < 3; dc++) {
                const int tap  = dr * 3 + dc;
                const int cc   = colb + dc;
                const int sw   = (((cc >> 1) ^ R) & 3) << 3;
                const int base = rb + cc * 32;
                bf16x8 a0 = *(const bf16x8*)&h1s[base + (cib ^ sw)];
                bf16x8 a1 = *(const bf16x8*)&h1s[base + ((16 + cib) ^ sw)];
                accE = __builtin_amdgcn_mfma_f32_32x32x16_bf16(a0, breg[2 * tap],     accE, 0, 0, 0);
                accO = __builtin_amdgcn_mfma_f32_32x32x16_bf16(a1, breg[2 * tap + 1], accO, 0, 0, 0);
            }
        }

        int slg = 8 * Mt + lg;
        #pragma unroll
        for (int gg = 0; gg < 4; gg++) {
            if (slg < 98) {
                f32x4 mn = *(const f32x4*)&mneg[slg * 4];
                float v0 = accE[gg * 4 + 0] + accO[gg * 4 + 0] + mn[0];
                float v1 = accE[gg * 4 + 1] + accO[gg * 4 + 1] + mn[1];
                float v2 = accE[gg * 4 + 2] + accO[gg * 4 + 2] + mn[2];
                float v3 = accE[gg * 4 + 3] + accO[gg * 4 + 3] + mn[3];
                float pm = fmaxf(fmaxf(v0, v1), fmaxf(v2, v3));
                pout[slg * 64] = (bf16)fmaxf(pm, 0.f);
            }
            slg += 2;
        }

        pj += 2; if (pj >= 14) { pj -= 14; pi += 1; }
        pi += 1;
    }

    // ---- Wl1-transpose epilogue (ex-prep_all blocks 0..391).
    // blockIdx-uniform branch: barriers are safe.  h1s reused as f32 tile
    // (32*129*4 = 16512 B <= 32768 B).  Runs in conv's block stream; done
    // before fc1 launches (kernel-ordering on the stream).
    if (blockIdx.x < 392) {
        __syncthreads();                    // all waves done with h1s
        float* tile = (float*)h1s;
        const int b  = blockIdx.x;
        const int s  = b >> 1;
        const int cg = b & 1;
        for (int e = t; e < 4096; e += 256) {
            int cl = e >> 7, n = e & 127;
            tile[cl * 129 + n] = Wl1[((long)(cg * 32 + cl) * 196 + s) * 128 + n];
        }
        __syncthreads();
        for (int e = t; e < 4096; e += 256) {
            int n = e >> 5, cl = e & 31;
            wl1t[(long)n * 12544 + s * 64 + cg * 32 + cl] = (bf16)tile[cl * 129 + n];
        }
    }
}

// ---------------------------------------------------------------------------
// fc1 R13 (RESTORED verbatim — best known; R22's zero-LDS streaming lost
// coalescing: 16B/lane at 25KB row stride = 64 cache lines per load ->
// +100 us.  Staged LDS converts strided rows into coalesced block loads.)
// bf16 MFMA split-K GEMM, BK=64, REGISTER-staged double buffer: load next
// tile into 20 VGPRs during compute, regs -> LDS (fast lgkm) before the
// barrier, so the vmcnt wait lands AFTER the MFMAs (m97 stall dodge).
// ks=7 slices of 1792 k. grid (128,7) = 896 blocks (co-resident at 4/CU).
// ---------------------------------------------------------------------------
__global__ __launch_bounds__(256, 4)
void fc1(const bf16* __restrict__ pooled, const bf16* __restrict__ wl1t,
         float* __restrict__ part)
{
    __shared__ __attribute__((aligned(16))) bf16 As[2][32 * 64];
    __shared__ __attribute__((aligned(16))) bf16 Bs[2][128 * 64];

    const int t    = threadIdx.x;
    const int lane = t & 63;
    const int wv   = t >> 6;
    const int ml   = lane & 15;
    const int kg   = lane >> 4;
    const int wm   = wv & 1;
    const int wn   = wv >> 1;
    const int m0   = blockIdx.x * 32;
    const int ks   = blockIdx.y;
    const int k0   = ks * 1792;

    // A: 256 chunks of 16B, 1/thread; chunk t -> As element t*8.
    // src: sub=(t>>7), i=t&127, r=i>>2, jq=(i&3)^((r>>1)&3)
    const bf16* asrc;
    {
        int sub = t >> 7, i = t & 127;
        int r  = i >> 2;
        int jq = (i & 3) ^ ((r >> 1) & 3);
        asrc = pooled + (long)(m0 + r) * 12544 + k0 + sub * 32 + jq * 8;
    }
    // B: 1024 chunks, 4/thread; chunk c=u*256+t -> Bs element c*8.
    const bf16* bsrc[4];
    #pragma unroll
    for (int u = 0; u < 4; u++) {
        int c  = u * 256 + t;
        int sub = c >> 9, i = c & 511;
        int r  = i >> 2;
        int jq = (i & 3) ^ ((r >> 1) & 3);
        bsrc[u] = wl1t + (long)r * 12544 + k0 + sub * 32 + jq * 8;
    }

    const int am = wm * 16 + ml;
    int aoff[2], boff[4];
    #pragma unroll
    for (int s = 0; s < 2; s++)
        aoff[s] = s * 1024 + ((am * 32 + kg * 8) ^ ((am & 6) << 2));
    #pragma unroll
    for (int j = 0; j < 4; j++) {
        int n = wn * 64 + j * 16 + ml;
        boff[j] = (n * 32 + kg * 8) ^ ((n & 6) << 2);
    }

    f32x4 acc[4];
    {
        f32x4 z = {0.f, 0.f, 0.f, 0.f};
        #pragma unroll
        for (int j = 0; j < 4; j++) acc[j] = z;
    }

    // prologue: tile 0 -> regs -> LDS[0]
    u32x4 ra = *(const u32x4*)asrc;
    u32x4 rb[4];
    #pragma unroll
    for (int u = 0; u < 4; u++) rb[u] = *(const u32x4*)bsrc[u];
    *(u32x4*)&As[0][t * 8] = ra;
    #pragma unroll
    for (int u = 0; u < 4; u++) *(u32x4*)&Bs[0][(u * 256 + t) * 8] = rb[u];

    for (int kt = 0; kt < 28; kt++) {
        __syncthreads();                    // buf[cur] visible; buf[nxt] free
        const int cur = kt & 1;
        if (kt < 27) {                      // prefetch kt+1 into registers
            const int kb = (kt + 1) * 64;
            ra = *(const u32x4*)(asrc + kb);
            #pragma unroll
            for (int u = 0; u < 4; u++) rb[u] = *(const u32x4*)(bsrc[u] + kb);
        }
        #pragma unroll
        for (int s = 0; s < 2; s++) {       // compute on cur (hides load latency)
            bf16x8 af = *(const bf16x8*)&As[cur][aoff[s]];
            #pragma unroll
            for (int j = 0; j < 4; j++) {
                bf16x8 bf = *(const bf16x8*)&Bs[cur][s * 4096 + boff[j]];
                acc[j] = __builtin_amdgcn_mfma_f32_16x16x32_bf16(af, bf, acc[j], 0, 0, 0);
            }
        }
        if (kt < 27) {                      // regs -> LDS[nxt] (vmcnt wait here)
            *(u32x4*)&As[cur ^ 1][t * 8] = ra;
            #pragma unroll
            for (int u = 0; u < 4; u++)
                *(u32x4*)&Bs[cur ^ 1][(u * 256 + t) * 8] = rb[u];
        }
    }

    float* pp = part + ((long)ks * 4096 + m0 + wm * 16) * 128 + wn * 64;
    #pragma unroll
    for (int j = 0; j < 4; j++)
        #pragma unroll
        for (int r = 0; r < 4; r++)
            pp[(kg * 4 + r) * 128 + j * 16 + ml] = acc[j][r];
}

// ---------------------------------------------------------------------------
// fc2_lsm: one wave per image; 7-way split-K reduce + FC2 + log_softmax.
// ---------------------------------------------------------------------------
__global__ __launch_bounds__(256)
void fc2_lsm(const float* __restrict__ part, const float* __restrict__ bl1,
             const float* __restrict__ Wl2, const float* __restrict__ bl2,
             float* __restrict__ out)
{
    const int wv   = threadIdx.x >> 6;
    const int lane = threadIdx.x & 63;
    const int img  = blockIdx.x * 4 + wv;
    const float* pb = part + (long)img * 128;

    float ac[10];
    #pragma unroll
    for (int c = 0; c < 10; c++) ac[c] = 0.f;

    #pragma unroll
    for (int u = 0; u < 2; u++) {
        int n = lane + 64 * u;
        float s = bl1[n];
        #pragma unroll
        for (int k = 0; k < 7; k++) s += pb[(long)k * 4096 * 128 + n];
        float h = s > 0.f ? s : 0.f;
        #pragma unroll
        for (int c = 0; c < 10; c++) ac[c] += h * Wl2[n * 10 + c];
    }
    #pragma unroll
    for (int o = 32; o > 0; o >>= 1)
        #pragma unroll
        for (int c = 0; c < 10; c++) ac[c] += __shfl_down(ac[c], o, 64);

    if (lane == 0) {
        float lg[10], mx = -1e30f;
        #pragma unroll
        for (int c = 0; c < 10; c++) {
            lg[c] = ac[c] + bl2[c];
            mx = lg[c] > mx ? lg[c] : mx;
        }
        float se = 0.f;
        #pragma unroll
        for (int c = 0; c < 10; c++) se += __expf(lg[c] - mx);
        float ls = __logf(se);
        #pragma unroll
        for (int c = 0; c < 10; c++) out[img * 10 + c] = lg[c] - mx - ls;
    }
}

// ---------------------------------------------------------------------------
extern "C" void kernel_launch(void* const* d_in, const int* in_sizes, int n_in,
                              void* d_out, int out_size, void* d_ws, size_t ws_size,
                              hipStream_t stream) {
    const float* x   = (const float*)d_in[0];
    const float* W1  = (const float*)d_in[1];
    const float* b1  = (const float*)d_in[2];
    const float* W2  = (const float*)d_in[3];
    const float* b2  = (const float*)d_in[4];
    const float* Wl1 = (const float*)d_in[5];
    const float* bl1 = (const float*)d_in[6];
    const float* Wl2 = (const float*)d_in[7];
    const float* bl2 = (const float*)d_in[8];
    float* out = (float*)d_out;

    char* ws = (char*)d_ws;
    bf16*  w2r    = (bf16*)ws;                                   // 36,864 B
    bf16*  w1f    = (bf16*)(ws + 40960);                         //  1,024 B
    bf16*  wl1t   = (bf16*)(ws + 65536);                         // 3,211,264 B
    bf16*  pooled = (bf16*)(ws + 65536 + 4194304);               // 102,760,448 B
    float* part   = (float*)(ws + 65536 + 4194304 + 102760448);  // 14,680,064 B

    prep_all  <<<74,             256, 0, stream>>>(W2, w2r, W1, w1f);
    conv_fused<<<8192,           256, 0, stream>>>(x, b1, w2r, w1f, b2, pooled, Wl1, wl1t);
    fc1       <<<dim3(128, 7),   256, 0, stream>>>(pooled, wl1t, part);
    fc2_lsm   <<<1024,           256, 0, stream>>>(part, bl1, Wl2, bl2, out);
}

// Round 13
// 252.234 us; speedup vs baseline: 1.3996x; 1.0176x over previous
//
#include <hip/hip_runtime.h>
#include <math.h>

typedef __bf16 bf16;
typedef __bf16 bf16x4 __attribute__((ext_vector_type(4)));
typedef __bf16 bf16x8 __attribute__((ext_vector_type(8)));
typedef unsigned short u16;
typedef unsigned short u16x4 __attribute__((ext_vector_type(4)));
typedef unsigned short u16x8 __attribute__((ext_vector_type(8)));
typedef float f32x4 __attribute__((ext_vector_type(4)));
typedef float f32x16 __attribute__((ext_vector_type(16)));
typedef unsigned int u32x4 __attribute__((ext_vector_type(4)));

// ---------------------------------------------------------------------------
// prep_all (original 466-block form, RESTORED — R23's transpose-fold into
// conv cost +5 us on conv for ~6 us serial saving: a wash; reverted).
// blocks [0,392): Wl1 f32 [12544][128] -> bf16 [128][12544], K permuted.
// blocks [392,466): W2 -> conv2 B-frag buffer w2r; W1 -> conv1 B-frag w1f.
// ---------------------------------------------------------------------------
__global__ void prep_all(const float* __restrict__ W2, bf16* __restrict__ w2r,
                         const float* __restrict__ W1, bf16* __restrict__ w1f,
                         const float* __restrict__ Wl1, bf16* __restrict__ wl1t) {
    __shared__ float tile[32 * 129];
    const int b = blockIdx.x;
    const int t = threadIdx.x;
    if (b < 392) {
        const int s  = b >> 1;
        const int cg = b & 1;
        for (int e = t; e < 4096; e += 256) {
            int cl = e >> 7, n = e & 127;
            tile[cl * 129 + n] = Wl1[((long)(cg * 32 + cl) * 196 + s) * 128 + n];
        }
        __syncthreads();
        for (int e = t; e < 4096; e += 256) {
            int n = e >> 5, cl = e & 31;
            wl1t[(long)n * 12544 + s * 64 + cg * 32 + cl] = (bf16)tile[cl * 129 + n];
        }
    } else {
        int e = (b - 392) * 256 + t;
        if (e < 18432) {
            int j  = e & 7;
            int l  = (e >> 3) & 63;
            int f  = e >> 9;
            int s  = f >> 1;
            int nt = f & 1;
            int tap  = s >> 1;
            int ci   = (s & 1) * 16 + (l >> 5) * 8 + j;
            int cout = nt * 32 + (l & 31);
            w2r[e] = (bf16)W2[cout * 288 + ci * 9 + tap];
        } else {
            int e2 = e - 18432;
            if (e2 < 512) {
                int j = e2 & 7;
                int l = e2 >> 3;
                int k = (l >> 5) * 8 + j;       // tap index (K)
                int n = l & 31;                 // cout
                w1f[e2] = (k < 9) ? (bf16)W1[n * 9 + k] : (bf16)0.f;
            }
        }
    }
}

// ---------------------------------------------------------------------------
// conv_fused R21 (FROZEN — structural local limit ~162 us):
// LDS ~60%, VALU ~59%, MFMA ~36%, reg-pinned 3 blk/CU.  Null levers:
// occupancy (R18/R19 spill -> (256,4) FORBIDDEN), MFMA chains (R20
// neutral), bank conflicts (R21: 1.75e7 -> 3.3e6, dur flat).
// !! e0a/e1a additive only (R14).  LDS fills > 256 elems: strided (R8).
// h1s: addr(R,C,ci) = R*1024 + C*32 + (ci ^ ((((C>>1)^R)&3)<<3)).
// ---------------------------------------------------------------------------
__global__ __launch_bounds__(256, 3)
void conv_fused(const float* __restrict__ x, const float* __restrict__ b1,
                const bf16* __restrict__ w2r, const bf16* __restrict__ w1f,
                const float* __restrict__ b2, bf16* __restrict__ pooled)
{
    __shared__ __attribute__((aligned(16))) bf16  h1s[16 * 1024];   // 32768 B
    __shared__ __attribute__((aligned(16))) float mneg[98 * 4];     //  1568 B
    __shared__ __attribute__((aligned(16))) bf16  xs[640];          //  1280 B

    const int t    = threadIdx.x;
    const int lane = t & 63;
    const int wv   = t >> 6;
    const int img  = blockIdx.x >> 1;
    const int hb   = blockIdx.x & 1;        // image half
    const int nt   = wv & 1;                // conv2 cout half
    const int wp   = wv >> 1;               // conv2 Mt parity
    const int ml31 = lane & 31;
    const int lg   = lane >> 5;

    const float* xi = x + img * 784;

    // global loads early (L2-resident; latency hides behind staging)
    bf16x8 breg[18];
    {
        const bf16x8* wp2 = (const bf16x8*)w2r;
        #pragma unroll
        for (int s = 0; s < 18; s++)
            breg[s] = wp2[(2 * s + nt) * 64 + lane];
    }
    const bf16x8 w1frag = *(const bf16x8*)&w1f[lane * 8];
    const float  bias2  = b2[nt * 32 + ml31];
    // conv1 bias, per-reg (cout = 4*lg + 8*run + j)
    f32x4 bq[4];
    #pragma unroll
    for (int run = 0; run < 4; run++)
        bq[run] = *(const f32x4*)&b1[4 * lg + 8 * run];

    // stage x tile (bf16): xs[j*32+c] = x[hb*14-2+j][c-1], rows 0..19 (pad)
    for (int e = t; e < 640; e += 256) {
        int j  = e >> 5;
        int c  = e & 31;
        int xr = hb * 14 - 2 + j;
        int xc = c - 1;
        float v = 0.f;
        if (xr >= 0 && xr < 28 && xc >= 0 && xc < 28) v = xi[xr * 28 + xc];
        xs[e] = (bf16)v;
    }
    __syncthreads();

    const u16* xu = (const u16*)xs;

    // mneg: 392 entries > 256 threads -> strided loop (R8 lesson)
    for (int e = t; e < 392; e += 256) {
        int s   = e >> 2, q = e & 3;
        int spi = s / 14, spj = s - spi * 14;
        u16 cv = xu[(2 * spi + (q >> 1) + 2) * 32 + 2 * spj + (q & 1) + 1];
        mneg[e] = ((cv & 0x7fff) != 0) ? 0.f : -1e30f;
    }

    // ---- conv1 via MFMA 32x32x16, im2col fused, operand-swapped (R16).
    // B-operand (af): lane = position col = ml31; lg picks K-half (taps).
    #pragma unroll 1
    for (int Mt = wv; Mt < 16; Mt += 4) {
        const int bb = Mt * 32 + ml31 - 1;      // window base in xu
        u16x8 tv;
        if (lg == 0) {
            tv[0] = xu[bb];      tv[1] = xu[bb + 1];  tv[2] = xu[bb + 2];
            tv[3] = xu[bb + 32]; tv[4] = xu[bb + 33]; tv[5] = xu[bb + 34];
            tv[6] = xu[bb + 64]; tv[7] = xu[bb + 65];
        } else {
            #pragma unroll
            for (int j = 0; j < 8; j++) tv[j] = 0;
            tv[0] = xu[bb + 66];                // tap 8
        }
        bf16x8 af = *(bf16x8*)&tv;

        f32x16 acc;
        #pragma unroll
        for (int run = 0; run < 4; run++)
            #pragma unroll
            for (int j = 0; j < 4; j++) acc[run * 4 + j] = bq[run][j];
        acc = __builtin_amdgcn_mfma_f32_32x32x16_bf16(w1frag, af, acc, 0, 0, 0);

        // mask: uniform per lane (one position)
        u16 ctr = xu[(Mt + 1) * 32 + ml31];
        const bool ok = (ml31 >= 1) && (ml31 <= 28) && ((ctr & 0x7fff) != 0);
        // write: addr = Mt*1024 + col*32 + (ci0 ^ swz), swz=(((col>>1)^Mt)&3)<<3
        const int hi2w  = ((ml31 >> 1) ^ Mt) & 3;
        const int wbase = (Mt << 10) + ml31 * 32 + 4 * lg;
        #pragma unroll
        for (int run = 0; run < 4; run++) {
            bf16x4 w4;
            #pragma unroll
            for (int j = 0; j < 4; j++) {
                float s = acc[run * 4 + j];
                w4[j] = (bf16)(ok ? fmaxf(s, 0.f) : 0.f);   // select: NaN-safe
            }
            *(bf16x4*)&h1s[wbase + 8 * (run ^ hi2w)] = w4;
        }
    }
    __syncthreads();    // h1s + mneg ready

    // ---- conv2 Mt loop (13 tiles of 32 M-rows, 98 pooled sites)
    const int cib = lg * 8;

    int q  = ml31 & 3;
    int pj = wp * 8 + (ml31 >> 2);
    int pi = 0;
    if (pj >= 14) { pj -= 14; pi = 1; }

    bf16* pout = pooled + (long)img * 12544 + hb * 98 * 64 + nt * 32 + ml31;

    #pragma unroll 1
    for (int Mt = wp; Mt < 13; Mt += 2) {
        int row = 2 * pi + (q >> 1);
        if (row > 13) row = 13;             // keep reads (row+2) in bounds
        int colb = 2 * pj + (q & 1);

        // Dual accumulators (R20; neutral, kept for chain ILP).
        f32x16 accE, accO;
        #pragma unroll
        for (int e = 0; e < 16; e++) { accE[e] = bias2; accO[e] = 0.f; }

        #pragma unroll
        for (int dr = 0; dr < 3; dr++) {
            const int R  = row + dr;
            const int rb = R << 10;         // * 1024
            #pragma unroll
            for (int dc = 0; dc < 3; dc++) {
                const int tap  = dr * 3 + dc;
                const int cc   = colb + dc;
                const int sw   = (((cc >> 1) ^ R) & 3) << 3;
                const int base = rb + cc * 32;
                bf16x8 a0 = *(const bf16x8*)&h1s[base + (cib ^ sw)];
                bf16x8 a1 = *(const bf16x8*)&h1s[base + ((16 + cib) ^ sw)];
                accE = __builtin_amdgcn_mfma_f32_32x32x16_bf16(a0, breg[2 * tap],     accE, 0, 0, 0);
                accO = __builtin_amdgcn_mfma_f32_32x32x16_bf16(a1, breg[2 * tap + 1], accO, 0, 0, 0);
            }
        }

        int slg = 8 * Mt + lg;
        #pragma unroll
        for (int gg = 0; gg < 4; gg++) {
            if (slg < 98) {
                f32x4 mn = *(const f32x4*)&mneg[slg * 4];
                float v0 = accE[gg * 4 + 0] + accO[gg * 4 + 0] + mn[0];
                float v1 = accE[gg * 4 + 1] + accO[gg * 4 + 1] + mn[1];
                float v2 = accE[gg * 4 + 2] + accO[gg * 4 + 2] + mn[2];
                float v3 = accE[gg * 4 + 3] + accO[gg * 4 + 3] + mn[3];
                float pm = fmaxf(fmaxf(v0, v1), fmaxf(v2, v3));
                pout[slg * 64] = (bf16)fmaxf(pm, 0.f);
            }
            slg += 2;
        }

        pj += 2; if (pj >= 14) { pj -= 14; pi += 1; }
        pi += 1;
    }
}

// ---------------------------------------------------------------------------
// fc1 R24: BM 32 -> 64 (grid (64,7), 448 blocks).  Same 28 K-iterations,
// but per iteration each wave now issues 16 MFMAs with 12 ds_reads (was
// 8 with 10): barrier events per FLOP halve, MFMA:LDS ratio 0.8 -> 1.33,
// and each staged B-tile is amortized over 64 A-rows (L2 B-traffic /2).
// A-staging = the PROVEN 32x64 chunk layout instantiated twice:
//   chunk c (512, 2/thread): half=c>>8, cc=c&255, sub=cc>>7, i=cc&127,
//   r=i>>2, jq=(i&3)^((r>>1)&3); src row = m0+half*32+r; dst elem = c*8.
//   Read: aoff[mi][s] = mi*2048 + s*1024 + ((am*32+kg*8) ^ ((am&6)<<2)),
//   am = wm*16+ml  (identity re-derived: q = jq ^ ((r>>1)&3) inverts).
// B path byte-identical to R13.  LDS 48 KiB -> (256,3); regs ~110 < 170.
// Register-staged double buffer kept (R13's m97-stall dodge).
// !! If total >= 250: BM=64 occupancy loss ate the gain -> revert to R13.
// ---------------------------------------------------------------------------
__global__ __launch_bounds__(256, 3)
void fc1(const bf16* __restrict__ pooled, const bf16* __restrict__ wl1t,
         float* __restrict__ part)
{
    __shared__ __attribute__((aligned(16))) bf16 As[2][64 * 64];
    __shared__ __attribute__((aligned(16))) bf16 Bs[2][128 * 64];

    const int t    = threadIdx.x;
    const int lane = t & 63;
    const int wv   = t >> 6;
    const int ml   = lane & 15;
    const int kg   = lane >> 4;
    const int wm   = wv & 1;
    const int wn   = wv >> 1;
    const int m0   = blockIdx.x * 64;
    const int ks   = blockIdx.y;
    const int k0   = ks * 1792;

    // A: 512 chunks of 16B, 2/thread; chunk c -> As element c*8.
    const bf16* asrc[2];
    #pragma unroll
    for (int u = 0; u < 2; u++) {
        int c    = u * 256 + t;
        int half = c >> 8, cc = c & 255;
        int sub  = cc >> 7, i = cc & 127;
        int r  = i >> 2;
        int jq = (i & 3) ^ ((r >> 1) & 3);
        asrc[u] = pooled + (long)(m0 + half * 32 + r) * 12544 + k0 + sub * 32 + jq * 8;
    }
    // B: 1024 chunks, 4/thread; chunk c=u*256+t -> Bs element c*8.
    const bf16* bsrc[4];
    #pragma unroll
    for (int u = 0; u < 4; u++) {
        int c  = u * 256 + t;
        int sub = c >> 9, i = c & 511;
        int r  = i >> 2;
        int jq = (i & 3) ^ ((r >> 1) & 3);
        bsrc[u] = wl1t + (long)r * 12544 + k0 + sub * 32 + jq * 8;
    }

    const int am = wm * 16 + ml;
    int aoff[2][2], boff[4];
    #pragma unroll
    for (int mi = 0; mi < 2; mi++)
        #pragma unroll
        for (int s = 0; s < 2; s++)
            aoff[mi][s] = mi * 2048 + s * 1024 + ((am * 32 + kg * 8) ^ ((am & 6) << 2));
    #pragma unroll
    for (int j = 0; j < 4; j++) {
        int n = wn * 64 + j * 16 + ml;
        boff[j] = (n * 32 + kg * 8) ^ ((n & 6) << 2);
    }

    f32x4 acc[2][4];
    {
        f32x4 z = {0.f, 0.f, 0.f, 0.f};
        #pragma unroll
        for (int mi = 0; mi < 2; mi++)
            #pragma unroll
            for (int j = 0; j < 4; j++) acc[mi][j] = z;
    }

    // prologue: tile 0 -> regs -> LDS[0]
    u32x4 ra[2], rb[4];
    #pragma unroll
    for (int u = 0; u < 2; u++) ra[u] = *(const u32x4*)asrc[u];
    #pragma unroll
    for (int u = 0; u < 4; u++) rb[u] = *(const u32x4*)bsrc[u];
    #pragma unroll
    for (int u = 0; u < 2; u++) *(u32x4*)&As[0][(u * 256 + t) * 8] = ra[u];
    #pragma unroll
    for (int u = 0; u < 4; u++) *(u32x4*)&Bs[0][(u * 256 + t) * 8] = rb[u];

    for (int kt = 0; kt < 28; kt++) {
        __syncthreads();                    // buf[cur] visible; buf[nxt] free
        const int cur = kt & 1;
        if (kt < 27) {                      // prefetch kt+1 into registers
            const int kb = (kt + 1) * 64;
            #pragma unroll
            for (int u = 0; u < 2; u++) ra[u] = *(const u32x4*)(asrc[u] + kb);
            #pragma unroll
            for (int u = 0; u < 4; u++) rb[u] = *(const u32x4*)(bsrc[u] + kb);
        }
        #pragma unroll
        for (int s = 0; s < 2; s++) {       // compute on cur (hides load latency)
            bf16x8 af0 = *(const bf16x8*)&As[cur][aoff[0][s]];
            bf16x8 af1 = *(const bf16x8*)&As[cur][aoff[1][s]];
            #pragma unroll
            for (int j = 0; j < 4; j++) {
                bf16x8 bf = *(const bf16x8*)&Bs[cur][s * 4096 + boff[j]];
                acc[0][j] = __builtin_amdgcn_mfma_f32_16x16x32_bf16(af0, bf, acc[0][j], 0, 0, 0);
                acc[1][j] = __builtin_amdgcn_mfma_f32_16x16x32_bf16(af1, bf, acc[1][j], 0, 0, 0);
            }
        }
        if (kt < 27) {                      // regs -> LDS[nxt] (vmcnt wait here)
            #pragma unroll
            for (int u = 0; u < 2; u++)
                *(u32x4*)&As[cur ^ 1][(u * 256 + t) * 8] = ra[u];
            #pragma unroll
            for (int u = 0; u < 4; u++)
                *(u32x4*)&Bs[cur ^ 1][(u * 256 + t) * 8] = rb[u];
        }
    }

    #pragma unroll
    for (int mi = 0; mi < 2; mi++) {
        float* pp = part + ((long)ks * 4096 + m0 + mi * 32 + wm * 16) * 128 + wn * 64;
        #pragma unroll
        for (int j = 0; j < 4; j++)
            #pragma unroll
            for (int r = 0; r < 4; r++)
                pp[(kg * 4 + r) * 128 + j * 16 + ml] = acc[mi][j][r];
    }
}

// ---------------------------------------------------------------------------
// fc2_lsm: one wave per image; 7-way split-K reduce + FC2 + log_softmax.
// ---------------------------------------------------------------------------
__global__ __launch_bounds__(256)
void fc2_lsm(const float* __restrict__ part, const float* __restrict__ bl1,
             const float* __restrict__ Wl2, const float* __restrict__ bl2,
             float* __restrict__ out)
{
    const int wv   = threadIdx.x >> 6;
    const int lane = threadIdx.x & 63;
    const int img  = blockIdx.x * 4 + wv;
    const float* pb = part + (long)img * 128;

    float ac[10];
    #pragma unroll
    for (int c = 0; c < 10; c++) ac[c] = 0.f;

    #pragma unroll
    for (int u = 0; u < 2; u++) {
        int n = lane + 64 * u;
        float s = bl1[n];
        #pragma unroll
        for (int k = 0; k < 7; k++) s += pb[(long)k * 4096 * 128 + n];
        float h = s > 0.f ? s : 0.f;
        #pragma unroll
        for (int c = 0; c < 10; c++) ac[c] += h * Wl2[n * 10 + c];
    }
    #pragma unroll
    for (int o = 32; o > 0; o >>= 1)
        #pragma unroll
        for (int c = 0; c < 10; c++) ac[c] += __shfl_down(ac[c], o, 64);

    if (lane == 0) {
        float lg[10], mx = -1e30f;
        #pragma unroll
        for (int c = 0; c < 10; c++) {
            lg[c] = ac[c] + bl2[c];
            mx = lg[c] > mx ? lg[c] : mx;
        }
        float se = 0.f;
        #pragma unroll
        for (int c = 0; c < 10; c++) se += __expf(lg[c] - mx);
        float ls = __logf(se);
        #pragma unroll
        for (int c = 0; c < 10; c++) out[img * 10 + c] = lg[c] - mx - ls;
    }
}

// ---------------------------------------------------------------------------
extern "C" void kernel_launch(void* const* d_in, const int* in_sizes, int n_in,
                              void* d_out, int out_size, void* d_ws, size_t ws_size,
                              hipStream_t stream) {
    const float* x   = (const float*)d_in[0];
    const float* W1  = (const float*)d_in[1];
    const float* b1  = (const float*)d_in[2];
    const float* W2  = (const float*)d_in[3];
    const float* b2  = (const float*)d_in[4];
    const float* Wl1 = (const float*)d_in[5];
    const float* bl1 = (const float*)d_in[6];
    const float* Wl2 = (const float*)d_in[7];
    const float* bl2 = (const float*)d_in[8];
    float* out = (float*)d_out;

    char* ws = (char*)d_ws;
    bf16*  w2r    = (bf16*)ws;                                   // 36,864 B
    bf16*  w1f    = (bf16*)(ws + 40960);                         //  1,024 B
    bf16*  wl1t   = (bf16*)(ws + 65536);                         // 3,211,264 B
    bf16*  pooled = (bf16*)(ws + 65536 + 4194304);               // 102,760,448 B
    float* part   = (float*)(ws + 65536 + 4194304 + 102760448);  // 14,680,064 B

    prep_all  <<<466,            256, 0, stream>>>(W2, w2r, W1, w1f, Wl1, wl1t);
    conv_fused<<<8192,           256, 0, stream>>>(x, b1, w2r, w1f, b2, pooled);
    fc1       <<<dim3(64, 7),    256, 0, stream>>>(pooled, wl1t, part);
    fc2_lsm   <<<1024,           256, 0, stream>>>(part, bl1, Wl2, bl2, out);
}